// Round 1
// baseline (82.188 us; speedup 1.0000x reference)
//
#include <hip/hip_runtime.h>

#define BB 8
#define TT 128
#define DD 256
#define BT (BB * TT)        // 1024 (b,t) pairs
#define SZ (BT * DD)        // 262144 floats per partial plane
#define LOG2E 1.44269504088896340736f

// Phase 1 (R6): one block per (b, t, k-half). Thread tid owns output column
// q = tid. ZERO memory ops in the inner loop: each wave holds this half's 128
// dec/enc values in registers (2 per lane) and broadcasts lane i to all lanes
// with ds_bpermute (uniform address = same-lane broadcast, no LDS storage, no
// bank conflicts). This removes the load->lgkmcnt(0)-drain->compute structure
// shared by R4 (LDS) and R5 (SMEM) -- the suspected stall wall -- and the
// k-split doubles the grid to 2048 blocks -> 8 blocks/CU -> 8 waves/SIMD.
// Inner iter: 1 shl + 4 bpermute (LDS pipe) + 4 mul + 4 v_exp + 4 add.
// If trans is quarter-rate this is trans-bound: ~7us for all of phase 1.
__global__ __launch_bounds__(256, 8) void attn_part_kernel(
    const float* __restrict__ dec,   // [B, D]
    const float* __restrict__ enc,   // [B, T, D]
    float* __restrict__ ws) {        // [4][BT][DD]: {cs_h0, cs_h1, rs_h0, rs_h1}
    const int blk = blockIdx.x >> 1;     // b*TT + t
    const int h   = blockIdx.x & 1;      // k-half: p,r in [h*128, h*128+128)
    const int b   = blk >> 7;
    const int tid = threadIdx.x;         // q
    const int l   = tid & 63;            // lane

    const float* __restrict__ drow = dec + b * DD;
    const float* __restrict__ erow = enc + blk * DD;

    // own-column operands (per-lane, coalesced)
    const float el2 = erow[tid] * LOG2E;   // colsum arg: exp2(d_p * el2)
    const float dl2 = drow[tid] * LOG2E;   // rowsum arg: exp2(dl2 * e_r)

    // this half's 128 broadcast operands, spread across the wave's 64 lanes
    const int hb = h * 128;
    const int dv0 = __float_as_int(drow[hb + l]);
    const int dv1 = __float_as_int(drow[hb + 64 + l]);
    const int ev0 = __float_as_int(erow[hb + l]);
    const int ev1 = __float_as_int(erow[hb + 64 + l]);

    float cs0 = 0.f, cs1 = 0.f, rs0 = 0.f, rs1 = 0.f;
    #pragma unroll 4
    for (int i = 0; i < 64; ++i) {
        const int a = i << 2;            // byte address of source lane
        const float d0 = __int_as_float(__builtin_amdgcn_ds_bpermute(a, dv0));
        const float d1 = __int_as_float(__builtin_amdgcn_ds_bpermute(a, dv1));
        const float e0 = __int_as_float(__builtin_amdgcn_ds_bpermute(a, ev0));
        const float e1 = __int_as_float(__builtin_amdgcn_ds_bpermute(a, ev1));
        cs0 += __builtin_amdgcn_exp2f(d0 * el2);
        cs1 += __builtin_amdgcn_exp2f(d1 * el2);
        rs0 += __builtin_amdgcn_exp2f(dl2 * e0);
        rs1 += __builtin_amdgcn_exp2f(dl2 * e1);
    }

    const int o = blk * DD + tid;
    ws[h * SZ + o]       = cs0 + cs1;    // colsum partial (this half)
    ws[(2 + h) * SZ + o] = rs0 + rs1;    // rowsum partial (this half)
}

// Phase 2: 32 blocks = (b, 64-wide q-slice). 256 threads = 4 t-chunks x 64 q.
// Combines the two k-halves (division is nonlinear -> must happen after both
// partials exist), multiplies by enc, sums over t. All 5 streams coalesced
// (lanes read consecutive q); data is L2/L3 resident (5 MB total).
__global__ __launch_bounds__(256) void reduce_t_kernel(
    const float* __restrict__ ws, const float* __restrict__ enc,
    float* __restrict__ out) {
    __shared__ float red[4][64];
    const int b = blockIdx.x >> 2;
    const int qc = blockIdx.x & 3;
    const int qlane = threadIdx.x & 63;
    const int tc = threadIdx.x >> 6;         // 0..3
    const int q = qc * 64 + qlane;

    const int base = (b * TT + tc * 32) * DD + q;
    float a0 = 0.f, a1 = 0.f, a2 = 0.f, a3 = 0.f;
    #pragma unroll 4
    for (int t = 0; t < 32; t += 4) {
        const int i0 = base + (t + 0) * DD;
        const int i1 = base + (t + 1) * DD;
        const int i2 = base + (t + 2) * DD;
        const int i3 = base + (t + 3) * DD;
        a0 += enc[i0] * (ws[i0] + ws[SZ + i0]) / (ws[2 * SZ + i0] + ws[3 * SZ + i0]);
        a1 += enc[i1] * (ws[i1] + ws[SZ + i1]) / (ws[2 * SZ + i1] + ws[3 * SZ + i1]);
        a2 += enc[i2] * (ws[i2] + ws[SZ + i2]) / (ws[2 * SZ + i2] + ws[3 * SZ + i2]);
        a3 += enc[i3] * (ws[i3] + ws[SZ + i3]) / (ws[2 * SZ + i3] + ws[3 * SZ + i3]);
    }
    red[tc][qlane] = (a0 + a1) + (a2 + a3);
    __syncthreads();
    if (tc == 0)
        out[b * DD + q] = red[0][qlane] + red[1][qlane] +
                          red[2][qlane] + red[3][qlane];
}

extern "C" void kernel_launch(void* const* d_in, const int* in_sizes, int n_in,
                              void* d_out, int out_size, void* d_ws, size_t ws_size,
                              hipStream_t stream) {
    const float* dec = (const float*)d_in[0];  // [B, D] fp32
    const float* enc = (const float*)d_in[1];  // [B, T, D] fp32
    float* out = (float*)d_out;                // [B, D] fp32
    float* ws = (float*)d_ws;                  // >= 4*BT*DD floats (4 MB)

    attn_part_kernel<<<BT * 2, 256, 0, stream>>>(dec, enc, ws);
    reduce_t_kernel<<<BB * 4, 256, 0, stream>>>(ws, enc, out);
}